// Round 1
// baseline (586.554 us; speedup 1.0000x reference)
//
#include <hip/hip_runtime.h>
#include <cstdint>
#include <cstddef>

using short8 = __attribute__((ext_vector_type(8))) short;
using f32x4  = __attribute__((ext_vector_type(4))) float;
using u16x4  = __attribute__((ext_vector_type(4))) unsigned short;

#define DEV __device__ __forceinline__

DEV unsigned short f2bf(float f) {
  unsigned int u = __builtin_bit_cast(unsigned int, f);
  u += 0x7fffu + ((u >> 16) & 1u);          // RNE
  return (unsigned short)(u >> 16);
}
DEV float bf2f(unsigned short h) {
  unsigned int u = ((unsigned int)h) << 16;
  return __builtin_bit_cast(float, u);
}

// direct global->LDS, width 16B (m97 lever). LDS dest = wave-uniform base + lane*16.
#define GLL16(gp, lp)                                                          \
  __builtin_amdgcn_global_load_lds(                                            \
      (const __attribute__((address_space(1))) char*)(const char*)(gp),        \
      (__attribute__((address_space(3))) char*)(char*)(lp), 16, 0, 0)

constexpr int BATCH = 2, SEQ = 2048, DMODEL = 2048, NH = 16, NKVH = 4, DH = 128;
constexpr int MROWS = BATCH * SEQ;            // 4096
constexpr int NQKV  = DMODEL + 2 * NKVH * DH; // 3072 (Q | K | V)
constexpr int KOFF  = DMODEL;                 // 2048
constexpr int VOFF  = DMODEL + NKVH * DH;     // 2560
constexpr float SM_SCALE = 0.08838834764831845f; // 1/sqrt(128)

// ---------------- prep kernels ----------------

__global__ void k_tables(float* __restrict__ tc, float* __restrict__ ts) {
  int id = blockIdx.x * 256 + threadIdx.x;    // SEQ*64 total
  int pos = id >> 6, i = id & 63;
  // inv_freq = 10000^(-i/64) = exp(-i * ln(10000)/64)
  float freq = __expf(-(float)i * 0.14391157f);
  float ang = (float)pos * freq;
  tc[id] = cosf(ang);
  ts[id] = sinf(ang);
}

__global__ void k_castx(const float* __restrict__ x, unsigned short* __restrict__ xb) {
  int id = blockIdx.x * 256 + threadIdx.x;    // MROWS*DMODEL/4 total
  float4 v = ((const float4*)x)[id];
  u16x4 o = { f2bf(v.x), f2bf(v.y), f2bf(v.z), f2bf(v.w) };
  ((u16x4*)xb)[id] = o;
}

// src: K(2048) x N fp32 row-major  ->  dst: N x 2048 bf16 row-major
__global__ __launch_bounds__(256) void k_wtrans(const float* __restrict__ src,
                                                unsigned short* __restrict__ dst, int N) {
  __shared__ float tile[32][33];
  int n0 = blockIdx.x * 32, k0 = blockIdx.y * 32;
  int tx = threadIdx.x, ty = threadIdx.y;     // 32 x 8
  #pragma unroll
  for (int r = ty; r < 32; r += 8)
    tile[r][tx] = src[(size_t)(k0 + r) * N + n0 + tx];
  __syncthreads();
  #pragma unroll
  for (int r = ty; r < 32; r += 8)
    dst[(size_t)(n0 + r) * 2048 + k0 + tx] = f2bf(tile[tx][r]);
}

// ---------------- GEMM: C[m][n] = sum_k A[m][k]*Bt[n][k]  (m97 structure) ----

constexpr int BM = 128, BN = 128, BK = 32;

template <bool OUTF32>
__global__ __launch_bounds__(256) void k_gemm_bt(
    const unsigned short* __restrict__ A,   // M x K bf16
    const unsigned short* __restrict__ Bt,  // N x K bf16
    void* __restrict__ C, int M, int N, int K) {
  __shared__ unsigned short As[BM * BK];
  __shared__ unsigned short Bs[BN * BK];
  const int t = threadIdx.x;
  const int l = t & 63, w = t >> 6;
  const int wm = w >> 1, wn = w & 1;
  const int m0 = blockIdx.y * BM, n0 = blockIdx.x * BN;
  const int rl = l & 15, kg = l >> 4;

  f32x4 acc[4][4] = {};

  // staging: thread t covers LDS bytes t*16 (+4096): row sr=t>>2 (64B rows of 4 chunks)
  // chunk-XOR swizzle via pre-permuted SOURCE (LDS dest stays linear), read side applies same XOR
  const int sr = t >> 2;
  const int gq = (t & 3) ^ (sr & 3);
  const unsigned short* aP0 = A  + (size_t)(m0 + sr) * K + gq * 8;
  const unsigned short* aP1 = A  + (size_t)(m0 + 64 + sr) * K + gq * 8;
  const unsigned short* bP0 = Bt + (size_t)(n0 + sr) * K + gq * 8;
  const unsigned short* bP1 = Bt + (size_t)(n0 + 64 + sr) * K + gq * 8;
  char* ldsA = (char*)As;
  char* ldsB = (char*)Bs;
  const int wb = w * 1024;

  const int nk = K / BK;
  for (int kt = 0; kt < nk; ++kt) {
    const int ko = kt * BK;
    __syncthreads();
    GLL16(aP0 + ko, ldsA + wb);
    GLL16(aP1 + ko, ldsA + 4096 + wb);
    GLL16(bP0 + ko, ldsB + wb);
    GLL16(bP1 + ko, ldsB + 4096 + wb);
    __syncthreads();   // drains vmcnt: LDS tiles ready
    short8 aF[4], bF[4];
    #pragma unroll
    for (int mi = 0; mi < 4; ++mi) {
      int r = wm * 64 + mi * 16 + rl;
      aF[mi] = *(const short8*)(ldsA + r * 64 + ((kg ^ (r & 3)) * 16));
    }
    #pragma unroll
    for (int ni = 0; ni < 4; ++ni) {
      int r = wn * 64 + ni * 16 + rl;
      bF[ni] = *(const short8*)(ldsB + r * 64 + ((kg ^ (r & 3)) * 16));
    }
    #pragma unroll
    for (int mi = 0; mi < 4; ++mi)
      #pragma unroll
      for (int ni = 0; ni < 4; ++ni)
        acc[mi][ni] = __builtin_amdgcn_mfma_f32_16x16x32_bf16(aF[mi], bF[ni], acc[mi][ni], 0, 0, 0);
  }

  // C/D layout (m89-verified): col = lane&15, row = (lane>>4)*4 + reg
  #pragma unroll
  for (int mi = 0; mi < 4; ++mi) {
    #pragma unroll
    for (int ni = 0; ni < 4; ++ni) {
      int row = m0 + wm * 64 + mi * 16 + kg * 4;
      int col = n0 + wn * 64 + ni * 16 + rl;
      #pragma unroll
      for (int r = 0; r < 4; ++r) {
        if constexpr (OUTF32)
          ((float*)C)[(size_t)(row + r) * N + col] = acc[mi][ni][r];
        else
          ((unsigned short*)C)[(size_t)(row + r) * N + col] = f2bf(acc[mi][ni][r]);
      }
    }
  }
}

// ---------------- RoPE (interleaved pairs) on Q and K regions of qkv --------

__global__ void k_rope(unsigned short* __restrict__ qkv,
                       const float* __restrict__ tc, const float* __restrict__ ts) {
  int id = blockIdx.x * 256 + threadIdx.x;     // MROWS * 1280
  int row = id / 1280, p = id % 1280;
  int col, d;
  if (p < 1024) { col = 2 * p;               d = p & 63; }          // Q: 16 heads
  else          { int pk = p - 1024; col = KOFF + 2 * pk; d = pk & 63; } // K: 4 heads
  int s = row & (SEQ - 1);
  float c = tc[s * 64 + d], sn = ts[s * 64 + d];
  unsigned int* pp = (unsigned int*)(qkv + (size_t)row * NQKV + col);
  unsigned int v = *pp;
  float x0 = bf2f((unsigned short)(v & 0xffffu));
  float x1 = bf2f((unsigned short)(v >> 16));
  float y0 = x0 * c - x1 * sn;
  float y1 = x1 * c + x0 * sn;
  *pp = (unsigned int)f2bf(y0) | ((unsigned int)f2bf(y1) << 16);
}

// ---------------- flash attention, causal, GQA ------------------------------
// block = 4 waves; wave w owns 16 q-rows; KVBLK=32 shared via LDS.

__global__ __launch_bounds__(256) void k_attn(const unsigned short* __restrict__ qkv,
                                              unsigned short* __restrict__ obuf) {
  __shared__ unsigned short Ks[32 * 128];   // K rows, 16B-chunk XOR ^(row&7)
  __shared__ unsigned short Vt[128 * 32];   // V^T rows, chunk XOR ^(row&3)
  __shared__ unsigned short Pw[4][16 * 32]; // per-wave P, chunk XOR ^(row&3)

  const int t = threadIdx.x, l = t & 63, w = t >> 6;
  const int rl = l & 15, kg = l >> 4;
  const int q0 = blockIdx.x * 64;
  const int h = blockIdx.y, b = blockIdx.z, kvh = h >> 2;
  const unsigned short* qbase = qkv + (size_t)b * SEQ * NQKV;
  const unsigned short* kbase = qbase + KOFF + kvh * DH;
  const unsigned short* vbase = qbase + VOFF + kvh * DH;

  // Q fragments hoisted: A[row=l&15][k=(l>>4)*8+j], 4 k-steps of 32
  short8 qF[4];
  {
    const int qrow = q0 + w * 16 + rl;
    #pragma unroll
    for (int ks = 0; ks < 4; ++ks)
      qF[ks] = *(const short8*)(qbase + (size_t)qrow * NQKV + h * DH + ks * 32 + kg * 8);
  }

  f32x4 Oc[8] = {};
  float mr[4], lr[4];
  #pragma unroll
  for (int r = 0; r < 4; ++r) { mr[r] = -3e38f; lr[r] = 0.f; }

  const int kvend = q0 + 64;
  for (int kv0 = 0; kv0 < kvend; kv0 += 32) {
    __syncthreads();
    // stage K (32x128) swizzled + V transposed (128x32) swizzled
    #pragma unroll
    for (int i = 0; i < 2; ++i) {
      int cid = t + i * 256;
      int krow = cid >> 4, c = cid & 15;
      size_t goff = (size_t)(kv0 + krow) * NQKV + c * 8;
      short8 kk = *(const short8*)(kbase + goff);
      *(short8*)&Ks[krow * 128 + (c ^ (krow & 7)) * 8] = kk;
      short8 vv = *(const short8*)(vbase + goff);
      #pragma unroll
      for (int j = 0; j < 8; ++j) {
        int dcol = c * 8 + j;
        Vt[dcol * 32 + (((krow >> 3) ^ (dcol & 3)) * 8) + (krow & 7)] = (unsigned short)vv[j];
      }
    }
    __syncthreads();

    // S = Q K^T : two 16x16 tiles over 32 kv cols
    f32x4 St0 = {}, St1 = {};
    #pragma unroll
    for (int ks = 0; ks < 4; ++ks) {
      int kr0 = rl, kr1 = 16 + rl;
      short8 kF0 = *(const short8*)&Ks[kr0 * 128 + (((ks * 4 + kg) ^ (kr0 & 7)) * 8)];
      short8 kF1 = *(const short8*)&Ks[kr1 * 128 + (((ks * 4 + kg) ^ (kr1 & 7)) * 8)];
      St0 = __builtin_amdgcn_mfma_f32_16x16x32_bf16(qF[ks], kF0, St0, 0, 0, 0);
      St1 = __builtin_amdgcn_mfma_f32_16x16x32_bf16(qF[ks], kF1, St1, 0, 0, 0);
    }

    // online softmax (row = kg*4+r, cols spread over 16-lane group)
    float p0v[4], p1v[4], sfv[4];
    #pragma unroll
    for (int r = 0; r < 4; ++r) {
      const int qg = q0 + w * 16 + kg * 4 + r;
      float s0 = St0[r] * SM_SCALE;
      float s1 = St1[r] * SM_SCALE;
      if (kv0 + rl > qg)      s0 = -3e38f;
      if (kv0 + 16 + rl > qg) s1 = -3e38f;
      float mx = fmaxf(s0, s1);
      #pragma unroll
      for (int dd = 1; dd < 16; dd <<= 1) mx = fmaxf(mx, __shfl_xor(mx, dd, 16));
      const float mnew = fmaxf(mr[r], mx);
      const float e0 = __expf(s0 - mnew);
      const float e1 = __expf(s1 - mnew);
      float rs = e0 + e1;
      #pragma unroll
      for (int dd = 1; dd < 16; dd <<= 1) rs += __shfl_xor(rs, dd, 16);
      const float sf = __expf(mr[r] - mnew);
      mr[r] = mnew;
      lr[r] = lr[r] * sf + rs;
      sfv[r] = sf; p0v[r] = e0; p1v[r] = e1;
    }

    // P -> LDS (per-wave region; same-wave RAW handled by compiler waits)
    unsigned short* pw = Pw[w];
    #pragma unroll
    for (int r = 0; r < 4; ++r) {
      const int pr = kg * 4 + r;
      pw[pr * 32 + (((rl >> 3) ^ (pr & 3)) * 8) + (rl & 7)]       = f2bf(p0v[r]);
      pw[pr * 32 + (((2 + (rl >> 3)) ^ (pr & 3)) * 8) + (rl & 7)] = f2bf(p1v[r]);
    }
    // rescale O
    #pragma unroll
    for (int c = 0; c < 8; ++c)
      #pragma unroll
      for (int r = 0; r < 4; ++r) Oc[c][r] *= sfv[r];

    // PV: A = P (16x32), B = V chunk (32x16) from Vt rows
    short8 pF = *(const short8*)&pw[rl * 32 + ((kg ^ (rl & 3)) * 8)];
    #pragma unroll
    for (int c = 0; c < 8; ++c) {
      const int vr = c * 16 + rl;
      short8 vF = *(const short8*)&Vt[vr * 32 + ((kg ^ (vr & 3)) * 8)];
      Oc[c] = __builtin_amdgcn_mfma_f32_16x16x32_bf16(pF, vF, Oc[c], 0, 0, 0);
    }
  }

  // epilogue: O /= l, write bf16 [b*S+s][h*128+d]
  float inv[4];
  #pragma unroll
  for (int r = 0; r < 4; ++r) inv[r] = 1.0f / lr[r];
  #pragma unroll
  for (int c = 0; c < 8; ++c)
    #pragma unroll
    for (int r = 0; r < 4; ++r) {
      int row = b * SEQ + q0 + w * 16 + kg * 4 + r;
      obuf[(size_t)row * DMODEL + h * DH + c * 16 + rl] = f2bf(Oc[c][r] * inv[r]);
    }
}

// ---------------- launch ----------------------------------------------------

extern "C" void kernel_launch(void* const* d_in, const int* in_sizes, int n_in,
                              void* d_out, int out_size, void* d_ws, size_t ws_size,
                              hipStream_t stream) {
  const float* x  = (const float*)d_in[0];
  const float* wq = (const float*)d_in[1];
  const float* wk = (const float*)d_in[2];
  const float* wv = (const float*)d_in[3];
  const float* wo = (const float*)d_in[4];
  float* out = (float*)d_out;

  unsigned short* xb  = (unsigned short*)d_ws;                 // 4096x2048
  unsigned short* wT  = xb  + (size_t)MROWS * DMODEL;          // 3072x2048 (q|k|v transposed)
  unsigned short* woT = wT  + (size_t)NQKV * DMODEL;           // 2048x2048
  unsigned short* qkv = woT + (size_t)DMODEL * DMODEL;         // 4096x3072
  unsigned short* ob  = qkv + (size_t)MROWS * NQKV;            // 4096x2048
  float* tc = (float*)(ob + (size_t)MROWS * DMODEL);           // 2048x64
  float* ts = tc + SEQ * 64;

  k_tables<<<dim3(SEQ * 64 / 256), dim3(256), 0, stream>>>(tc, ts);
  k_castx<<<dim3(MROWS * DMODEL / 4 / 256), dim3(256), 0, stream>>>(x, xb);
  k_wtrans<<<dim3(DMODEL / 32, 64), dim3(32, 8), 0, stream>>>(wq, wT, DMODEL);
  k_wtrans<<<dim3(NKVH * DH / 32, 64), dim3(32, 8), 0, stream>>>(wk, wT + (size_t)DMODEL * 2048, NKVH * DH);
  k_wtrans<<<dim3(NKVH * DH / 32, 64), dim3(32, 8), 0, stream>>>(wv, wT + (size_t)VOFF * 2048, NKVH * DH);
  k_wtrans<<<dim3(DMODEL / 32, 64), dim3(32, 8), 0, stream>>>(wo, woT, DMODEL);

  k_gemm_bt<false><<<dim3(NQKV / BN, MROWS / BM), dim3(256), 0, stream>>>(
      xb, wT, qkv, MROWS, NQKV, DMODEL);
  k_rope<<<dim3(MROWS * 1280 / 256), dim3(256), 0, stream>>>(qkv, tc, ts);
  k_attn<<<dim3(SEQ / 64, NH, BATCH), dim3(256), 0, stream>>>(qkv, ob);
  k_gemm_bt<true><<<dim3(DMODEL / BN, MROWS / BM), dim3(256), 0, stream>>>(
      ob, woT, out, MROWS, DMODEL, DMODEL);
}

// Round 2
// 381.868 us; speedup vs baseline: 1.5360x; 1.5360x over previous
//
#include <hip/hip_runtime.h>
#include <cstdint>
#include <cstddef>

using short8 = __attribute__((ext_vector_type(8))) short;
using f32x4  = __attribute__((ext_vector_type(4))) float;
using u16x4  = __attribute__((ext_vector_type(4))) unsigned short;

#define DEV __device__ __forceinline__

DEV unsigned short f2bf(float f) {
  unsigned int u = __builtin_bit_cast(unsigned int, f);
  u += 0x7fffu + ((u >> 16) & 1u);          // RNE
  return (unsigned short)(u >> 16);
}
DEV float bf2f(unsigned short h) {
  unsigned int u = ((unsigned int)h) << 16;
  return __builtin_bit_cast(float, u);
}

// direct global->LDS, width 16B (m97 lever). LDS dest = wave-uniform base + lane*16.
#define GLL16(gp, lp)                                                          \
  __builtin_amdgcn_global_load_lds(                                            \
      (const __attribute__((address_space(1))) char*)(const char*)(gp),        \
      (__attribute__((address_space(3))) char*)(char*)(lp), 16, 0, 0)

constexpr int BATCH = 2, SEQ = 2048, DMODEL = 2048, NH = 16, NKVH = 4, DH = 128;
constexpr int MROWS = BATCH * SEQ;            // 4096
constexpr int NQKV  = DMODEL + 2 * NKVH * DH; // 3072 (Q | K | V)
constexpr int KOFF  = DMODEL;                 // 2048
constexpr int VOFF  = DMODEL + NKVH * DH;     // 2560
constexpr float SM_SCALE = 0.08838834764831845f; // 1/sqrt(128)

// ---------------- prep kernels ----------------

__global__ void k_tables(float* __restrict__ tc, float* __restrict__ ts) {
  int id = blockIdx.x * 256 + threadIdx.x;    // SEQ*64 total
  int pos = id >> 6, i = id & 63;
  float freq = __expf(-(float)i * 0.14391157f);
  float ang = (float)pos * freq;
  tc[id] = cosf(ang);
  ts[id] = sinf(ang);
}

__global__ void k_castx(const float* __restrict__ x, unsigned short* __restrict__ xb) {
  int id = blockIdx.x * 256 + threadIdx.x;    // MROWS*DMODEL/4 total
  float4 v = ((const float4*)x)[id];
  u16x4 o = { f2bf(v.x), f2bf(v.y), f2bf(v.z), f2bf(v.w) };
  ((u16x4*)xb)[id] = o;
}

// src: K(2048) x N fp32 row-major  ->  dst: N x 2048 bf16 row-major
__global__ __launch_bounds__(256) void k_wtrans(const float* __restrict__ src,
                                                unsigned short* __restrict__ dst, int N) {
  __shared__ float tile[32][33];
  int n0 = blockIdx.x * 32, k0 = blockIdx.y * 32;
  int tx = threadIdx.x, ty = threadIdx.y;     // 32 x 8
  #pragma unroll
  for (int r = ty; r < 32; r += 8)
    tile[r][tx] = src[(size_t)(k0 + r) * N + n0 + tx];
  __syncthreads();
  #pragma unroll
  for (int r = ty; r < 32; r += 8)
    dst[(size_t)(n0 + r) * 2048 + k0 + tx] = f2bf(tile[tx][r]);
}

// V region of qkv -> vt[b][kvh][d=128][s=2048]  (bf16 -> bf16 transpose)
__global__ __launch_bounds__(256) void k_vtrans(const unsigned short* __restrict__ qkv,
                                                unsigned short* __restrict__ vt) {
  __shared__ unsigned short tile[32][33];
  int s0 = blockIdx.x * 32, d0 = blockIdx.y * 32;
  int bk = blockIdx.z;                         // b*4 + kvh
  const unsigned short* src = qkv + (size_t)(bk >> 2) * SEQ * NQKV + VOFF + (bk & 3) * DH;
  unsigned short* dst = vt + ((size_t)bk * DH + d0) * SEQ + s0;
  int tx = threadIdx.x, ty = threadIdx.y;      // 32 x 8
  #pragma unroll
  for (int r = ty; r < 32; r += 8)
    tile[r][tx] = src[(size_t)(s0 + r) * NQKV + d0 + tx];
  __syncthreads();
  #pragma unroll
  for (int r = ty; r < 32; r += 8)
    dst[(size_t)r * SEQ + tx] = tile[tx][r];
}

// ---------------- GEMM: C[m][n] = sum_k A[m][k]*Bt[n][k]  (m97 structure) ----

constexpr int BM = 128, BN = 128, BK = 32;

template <bool OUTF32>
__global__ __launch_bounds__(256) void k_gemm_bt(
    const unsigned short* __restrict__ A,   // M x K bf16
    const unsigned short* __restrict__ Bt,  // N x K bf16
    void* __restrict__ C, int M, int N, int K) {
  __shared__ unsigned short As[BM * BK];
  __shared__ unsigned short Bs[BN * BK];
  const int t = threadIdx.x;
  const int l = t & 63, w = t >> 6;
  const int wm = w >> 1, wn = w & 1;
  const int m0 = blockIdx.y * BM, n0 = blockIdx.x * BN;
  const int rl = l & 15, kg = l >> 4;

  f32x4 acc[4][4] = {};

  const int sr = t >> 2;
  const int gq = (t & 3) ^ (sr & 3);
  const unsigned short* aP0 = A  + (size_t)(m0 + sr) * K + gq * 8;
  const unsigned short* aP1 = A  + (size_t)(m0 + 64 + sr) * K + gq * 8;
  const unsigned short* bP0 = Bt + (size_t)(n0 + sr) * K + gq * 8;
  const unsigned short* bP1 = Bt + (size_t)(n0 + 64 + sr) * K + gq * 8;
  char* ldsA = (char*)As;
  char* ldsB = (char*)Bs;
  const int wb = w * 1024;

  const int nk = K / BK;
  for (int kt = 0; kt < nk; ++kt) {
    const int ko = kt * BK;
    __syncthreads();
    GLL16(aP0 + ko, ldsA + wb);
    GLL16(aP1 + ko, ldsA + 4096 + wb);
    GLL16(bP0 + ko, ldsB + wb);
    GLL16(bP1 + ko, ldsB + 4096 + wb);
    __syncthreads();
    short8 aF[4], bF[4];
    #pragma unroll
    for (int mi = 0; mi < 4; ++mi) {
      int r = wm * 64 + mi * 16 + rl;
      aF[mi] = *(const short8*)(ldsA + r * 64 + ((kg ^ (r & 3)) * 16));
    }
    #pragma unroll
    for (int ni = 0; ni < 4; ++ni) {
      int r = wn * 64 + ni * 16 + rl;
      bF[ni] = *(const short8*)(ldsB + r * 64 + ((kg ^ (r & 3)) * 16));
    }
    #pragma unroll
    for (int mi = 0; mi < 4; ++mi)
      #pragma unroll
      for (int ni = 0; ni < 4; ++ni)
        acc[mi][ni] = __builtin_amdgcn_mfma_f32_16x16x32_bf16(aF[mi], bF[ni], acc[mi][ni], 0, 0, 0);
  }

  // C/D layout (m89-verified): col = lane&15, row = (lane>>4)*4 + reg
  #pragma unroll
  for (int mi = 0; mi < 4; ++mi) {
    #pragma unroll
    for (int ni = 0; ni < 4; ++ni) {
      int row = m0 + wm * 64 + mi * 16 + kg * 4;
      int col = n0 + wn * 64 + ni * 16 + rl;
      #pragma unroll
      for (int r = 0; r < 4; ++r) {
        if constexpr (OUTF32)
          ((float*)C)[(size_t)(row + r) * N + col] = acc[mi][ni][r];
        else
          ((unsigned short*)C)[(size_t)(row + r) * N + col] = f2bf(acc[mi][ni][r]);
      }
    }
  }
}

// ---------------- RoPE (interleaved pairs) on Q and K regions of qkv --------

__global__ void k_rope(unsigned short* __restrict__ qkv,
                       const float* __restrict__ tc, const float* __restrict__ ts) {
  int id = blockIdx.x * 256 + threadIdx.x;     // MROWS * 1280
  int row = id / 1280, p = id % 1280;
  int col, d;
  if (p < 1024) { col = 2 * p;               d = p & 63; }
  else          { int pk = p - 1024; col = KOFF + 2 * pk; d = pk & 63; }
  int s = row & (SEQ - 1);
  float c = tc[s * 64 + d], sn = ts[s * 64 + d];
  unsigned int* pp = (unsigned int*)(qkv + (size_t)row * NQKV + col);
  unsigned int v = *pp;
  float x0 = bf2f((unsigned short)(v & 0xffffu));
  float x1 = bf2f((unsigned short)(v >> 16));
  float y0 = x0 * c - x1 * sn;
  float y1 = x1 * c + x0 * sn;
  *pp = (unsigned int)f2bf(y0) | ((unsigned int)f2bf(y1) << 16);
}

// ---------------- flash attention, causal, GQA ------------------------------
// 4 waves x 32 q-rows (QB=128), KVBLK=64; K/V staged via global_load_lds with
// pre-swizzled sources (rule #21: linear LDS dest + XOR on the read side).

constexpr int QB = 128, KB = 64;

__global__ __launch_bounds__(256) void k_attn(const unsigned short* __restrict__ qkv,
                                              const unsigned short* __restrict__ vt,
                                              unsigned short* __restrict__ obuf) {
  __shared__ unsigned short Ks[KB * DH];        // [64][128], chunk-XOR ^(row&7)
  __shared__ unsigned short Vs[DH * KB];        // [128][64], chunk-XOR ^(row&7)
  __shared__ unsigned short Pw[4][2][16 * 72];  // per-wave P, padded stride 72

  const int t = threadIdx.x, l = t & 63, w = t >> 6;
  const int rl = l & 15, kg = l >> 4;
  const int q0 = blockIdx.x * QB;
  const int h = blockIdx.y, b = blockIdx.z, kvh = h >> 2;
  const unsigned short* qbase = qkv + (size_t)b * SEQ * NQKV;
  const unsigned short* kbase = qbase + KOFF + kvh * DH;
  const unsigned short* vtb = vt + (size_t)(b * NKVH + kvh) * DH * SEQ;

  // pre-swizzled staging sources: chunk c = i*256+t; K: row=c>>4,q=c&15; V: row=c>>3,q=c&7
  const unsigned short* kp[4];
  const unsigned short* vp[4];
  #pragma unroll
  for (int i = 0; i < 4; ++i) {
    int ck = i * 256 + t;
    int krow = ck >> 4, kq = ck & 15;
    kp[i] = kbase + (size_t)krow * NQKV + ((kq ^ (krow & 7)) << 3);
    int vrow = ck >> 3, vq = ck & 7;
    vp[i] = vtb + (size_t)vrow * SEQ + ((vq ^ (vrow & 7)) << 3);
  }

  const int qw0 = q0 + w * 32;

  // Q fragments hoisted: A[row=rl][k=kg*8+j], 2 m-tiles x 4 k-steps
  short8 qF[2][4];
  #pragma unroll
  for (int m = 0; m < 2; ++m) {
    const size_t qr = (size_t)(qw0 + m * 16 + rl) * NQKV + h * DH;
    #pragma unroll
    for (int ks = 0; ks < 4; ++ks)
      qF[m][ks] = *(const short8*)(qbase + qr + ks * 32 + kg * 8);
  }

  f32x4 Oc[2][8] = {};
  float mr[2][4], lr[2][4];
  #pragma unroll
  for (int m = 0; m < 2; ++m)
    #pragma unroll
    for (int r = 0; r < 4; ++r) { mr[m][r] = -3e38f; lr[m][r] = 0.f; }

  unsigned short* pwm[2] = { Pw[w][0], Pw[w][1] };

  for (int kv0 = 0; kv0 < q0 + QB; kv0 += KB) {
    __syncthreads();
    #pragma unroll
    for (int i = 0; i < 4; ++i) {
      GLL16(kp[i] + (size_t)kv0 * NQKV, (char*)Ks + (i * 256 + w * 64) * 16);
      GLL16(vp[i] + kv0,               (char*)Vs + (i * 256 + w * 64) * 16);
    }
    __syncthreads();
    if (kv0 >= qw0 + 32) continue;   // fully masked for this wave (wave-uniform)

    // S = Q K^T : St[m][n], kv col tiles n of 16
    f32x4 St[2][4] = {};
    #pragma unroll
    for (int n = 0; n < 4; ++n) {
      const int krow = n * 16 + rl;
      #pragma unroll
      for (int ks = 0; ks < 4; ++ks) {
        short8 kF = *(const short8*)&Ks[krow * DH + (((ks * 4 + kg) ^ (rl & 7)) << 3)];
        St[0][n] = __builtin_amdgcn_mfma_f32_16x16x32_bf16(qF[0][ks], kF, St[0][n], 0, 0, 0);
        St[1][n] = __builtin_amdgcn_mfma_f32_16x16x32_bf16(qF[1][ks], kF, St[1][n], 0, 0, 0);
      }
    }

    // online softmax; rows per lane: (m, r) -> q row qw0+m*16+kg*4+r
    float sfv[2][4];
    #pragma unroll
    for (int m = 0; m < 2; ++m) {
      #pragma unroll
      for (int r = 0; r < 4; ++r) {
        const int qg = qw0 + m * 16 + kg * 4 + r;
        float e[4];
        float mx = -3e38f;
        #pragma unroll
        for (int n = 0; n < 4; ++n) {
          float s = St[m][n][r] * SM_SCALE;
          if (kv0 + n * 16 + rl > qg) s = -3e38f;
          e[n] = s;
          mx = fmaxf(mx, s);
        }
        #pragma unroll
        for (int dd = 1; dd < 16; dd <<= 1) mx = fmaxf(mx, __shfl_xor(mx, dd, 16));
        const float mnew = fmaxf(mr[m][r], mx);
        float rs = 0.f;
        #pragma unroll
        for (int n = 0; n < 4; ++n) { e[n] = __expf(e[n] - mnew); rs += e[n]; }
        #pragma unroll
        for (int dd = 1; dd < 16; dd <<= 1) rs += __shfl_xor(rs, dd, 16);
        const float sf = __expf(mr[m][r] - mnew);
        mr[m][r] = mnew;
        lr[m][r] = lr[m][r] * sf + rs;
        sfv[m][r] = sf;
        const int pr = kg * 4 + r;
        unsigned short* pw = pwm[m];
        #pragma unroll
        for (int n = 0; n < 4; ++n) pw[pr * 72 + n * 16 + rl] = f2bf(e[n]);
      }
    }

    // rescale O
    #pragma unroll
    for (int m = 0; m < 2; ++m)
      #pragma unroll
      for (int c = 0; c < 8; ++c)
        #pragma unroll
        for (int r = 0; r < 4; ++r) Oc[m][c][r] *= sfv[m][r];

    // PV: A = P[16][64] (row=rl, k=kv), B = V (col=d=rl, k=kv) from Vs rows
    short8 pF[2][2];
    #pragma unroll
    for (int m = 0; m < 2; ++m)
      #pragma unroll
      for (int ks2 = 0; ks2 < 2; ++ks2)
        pF[m][ks2] = *(const short8*)&pwm[m][rl * 72 + ks2 * 32 + kg * 8];
    #pragma unroll
    for (int c = 0; c < 8; ++c) {
      const int vrow = c * 16 + rl;
      #pragma unroll
      for (int ks2 = 0; ks2 < 2; ++ks2) {
        short8 vF = *(const short8*)&Vs[vrow * KB + (((ks2 * 4 + kg) ^ (rl & 7)) << 3)];
        Oc[0][c] = __builtin_amdgcn_mfma_f32_16x16x32_bf16(pF[0][ks2], vF, Oc[0][c], 0, 0, 0);
        Oc[1][c] = __builtin_amdgcn_mfma_f32_16x16x32_bf16(pF[1][ks2], vF, Oc[1][c], 0, 0, 0);
      }
    }
  }

  // epilogue: O /= l, write bf16 [b*S+s][h*128+d]
  #pragma unroll
  for (int m = 0; m < 2; ++m) {
    float inv[4];
    #pragma unroll
    for (int r = 0; r < 4; ++r) inv[r] = 1.0f / lr[m][r];
    #pragma unroll
    for (int c = 0; c < 8; ++c)
      #pragma unroll
      for (int r = 0; r < 4; ++r) {
        int row = b * SEQ + qw0 + m * 16 + kg * 4 + r;
        obuf[(size_t)row * DMODEL + h * DH + c * 16 + rl] = f2bf(Oc[m][c][r] * inv[r]);
      }
  }
}

// ---------------- launch ----------------------------------------------------

extern "C" void kernel_launch(void* const* d_in, const int* in_sizes, int n_in,
                              void* d_out, int out_size, void* d_ws, size_t ws_size,
                              hipStream_t stream) {
  const float* x  = (const float*)d_in[0];
  const float* wq = (const float*)d_in[1];
  const float* wk = (const float*)d_in[2];
  const float* wv = (const float*)d_in[3];
  const float* wo = (const float*)d_in[4];
  float* out = (float*)d_out;

  unsigned short* xb  = (unsigned short*)d_ws;                 // 4096x2048
  unsigned short* wT  = xb  + (size_t)MROWS * DMODEL;          // 3072x2048 (q|k|v transposed)
  unsigned short* woT = wT  + (size_t)NQKV * DMODEL;           // 2048x2048
  unsigned short* qkv = woT + (size_t)DMODEL * DMODEL;         // 4096x3072
  unsigned short* ob  = qkv + (size_t)MROWS * NQKV;            // 4096x2048
  float* tc = (float*)(ob + (size_t)MROWS * DMODEL);           // 2048x64
  float* ts = tc + SEQ * 64;
  // vt reuses the wT region (wT dead after the QKV GEMM): 2*4*128*2048 elems (4MB <= 12MB)
  unsigned short* vtG = wT;

  k_tables<<<dim3(SEQ * 64 / 256), dim3(256), 0, stream>>>(tc, ts);
  k_castx<<<dim3(MROWS * DMODEL / 4 / 256), dim3(256), 0, stream>>>(x, xb);
  k_wtrans<<<dim3(DMODEL / 32, 64), dim3(32, 8), 0, stream>>>(wq, wT, DMODEL);
  k_wtrans<<<dim3(NKVH * DH / 32, 64), dim3(32, 8), 0, stream>>>(wk, wT + (size_t)DMODEL * 2048, NKVH * DH);
  k_wtrans<<<dim3(NKVH * DH / 32, 64), dim3(32, 8), 0, stream>>>(wv, wT + (size_t)VOFF * 2048, NKVH * DH);
  k_wtrans<<<dim3(DMODEL / 32, 64), dim3(32, 8), 0, stream>>>(wo, woT, DMODEL);

  k_gemm_bt<false><<<dim3(NQKV / BN, MROWS / BM), dim3(256), 0, stream>>>(
      xb, wT, qkv, MROWS, NQKV, DMODEL);
  k_rope<<<dim3(MROWS * 1280 / 256), dim3(256), 0, stream>>>(qkv, tc, ts);
  k_vtrans<<<dim3(SEQ / 32, DH / 32, BATCH * NKVH), dim3(32, 8), 0, stream>>>(qkv, vtG);
  k_attn<<<dim3(SEQ / QB, NH, BATCH), dim3(256), 0, stream>>>(qkv, vtG, ob);
  k_gemm_bt<true><<<dim3(DMODEL / BN, MROWS / BM), dim3(256), 0, stream>>>(
      ob, woT, out, MROWS, DMODEL, DMODEL);
}

// Round 3
// 284.731 us; speedup vs baseline: 2.0600x; 1.3412x over previous
//
#include <hip/hip_runtime.h>
#include <cstdint>
#include <cstddef>

using short8 = __attribute__((ext_vector_type(8))) short;
using f32x4  = __attribute__((ext_vector_type(4))) float;
using u16x4  = __attribute__((ext_vector_type(4))) unsigned short;

#define DEV __device__ __forceinline__

DEV unsigned short f2bf(float f) {
  unsigned int u = __builtin_bit_cast(unsigned int, f);
  u += 0x7fffu + ((u >> 16) & 1u);          // RNE
  return (unsigned short)(u >> 16);
}
DEV float bf2f(unsigned short h) {
  unsigned int u = ((unsigned int)h) << 16;
  return __builtin_bit_cast(float, u);
}

// direct global->LDS, width 16B (m97 lever). LDS dest = wave-uniform base + lane*16.
#define GLL16(gp, lp)                                                          \
  __builtin_amdgcn_global_load_lds(                                            \
      (const __attribute__((address_space(1))) char*)(const char*)(gp),        \
      (__attribute__((address_space(3))) char*)(char*)(lp), 16, 0, 0)

constexpr int BATCH = 2, SEQ = 2048, DMODEL = 2048, NH = 16, NKVH = 4, DH = 128;
constexpr int MROWS = BATCH * SEQ;            // 4096
constexpr int NQKV  = DMODEL + 2 * NKVH * DH; // 3072 (Q | K | V)
constexpr int KOFF  = DMODEL;                 // 2048
constexpr int VOFF  = DMODEL + NKVH * DH;     // 2560
constexpr float SM_SCALE = 0.08838834764831845f;             // 1/sqrt(128)
constexpr float SM_L2 = 0.12751388158f;                      // SM_SCALE * log2(e)

// ---------------- prep kernels ----------------

__global__ void k_tables(float* __restrict__ tc, float* __restrict__ ts) {
  int id = blockIdx.x * 256 + threadIdx.x;    // SEQ*64 total
  int pos = id >> 6, i = id & 63;
  float freq = __expf(-(float)i * 0.14391157f);
  float ang = (float)pos * freq;
  tc[id] = cosf(ang);
  ts[id] = sinf(ang);
}

__global__ void k_castx(const float* __restrict__ x, unsigned short* __restrict__ xb) {
  int id = blockIdx.x * 256 + threadIdx.x;    // MROWS*DMODEL/4 total
  float4 v = ((const float4*)x)[id];
  u16x4 o = { f2bf(v.x), f2bf(v.y), f2bf(v.z), f2bf(v.w) };
  ((u16x4*)xb)[id] = o;
}

// src: K(2048) x N fp32 row-major  ->  dst: N x 2048 bf16 row-major
__global__ __launch_bounds__(256) void k_wtrans(const float* __restrict__ src,
                                                unsigned short* __restrict__ dst, int N) {
  __shared__ float tile[32][33];
  int n0 = blockIdx.x * 32, k0 = blockIdx.y * 32;
  int tx = threadIdx.x, ty = threadIdx.y;     // 32 x 8
  #pragma unroll
  for (int r = ty; r < 32; r += 8)
    tile[r][tx] = src[(size_t)(k0 + r) * N + n0 + tx];
  __syncthreads();
  #pragma unroll
  for (int r = ty; r < 32; r += 8)
    dst[(size_t)(n0 + r) * 2048 + k0 + tx] = f2bf(tile[tx][r]);
}

// V region of qkv -> vt[b][kvh][d=128][s=2048]  (bf16 -> bf16 transpose)
__global__ __launch_bounds__(256) void k_vtrans(const unsigned short* __restrict__ qkv,
                                                unsigned short* __restrict__ vt) {
  __shared__ unsigned short tile[32][33];
  int s0 = blockIdx.x * 32, d0 = blockIdx.y * 32;
  int bk = blockIdx.z;                         // b*4 + kvh
  const unsigned short* src = qkv + (size_t)(bk >> 2) * SEQ * NQKV + VOFF + (bk & 3) * DH;
  unsigned short* dst = vt + ((size_t)bk * DH + d0) * SEQ + s0;
  int tx = threadIdx.x, ty = threadIdx.y;      // 32 x 8
  #pragma unroll
  for (int r = ty; r < 32; r += 8)
    tile[r][tx] = src[(size_t)(s0 + r) * NQKV + d0 + tx];
  __syncthreads();
  #pragma unroll
  for (int r = ty; r < 32; r += 8)
    dst[(size_t)r * SEQ + tx] = tile[tx][r];
}

// ---------------- GEMM: C[m][n] = sum_k A[m][k]*Bt[n][k]  (m97 structure) ----

constexpr int BM = 128, BN = 128, BK = 32;

template <bool OUTF32>
__global__ __launch_bounds__(256) void k_gemm_bt(
    const unsigned short* __restrict__ A,   // M x K bf16
    const unsigned short* __restrict__ Bt,  // N x K bf16
    void* __restrict__ C, int M, int N, int K) {
  __shared__ unsigned short As[BM * BK];
  __shared__ unsigned short Bs[BN * BK];
  const int t = threadIdx.x;
  const int l = t & 63, w = t >> 6;
  const int wm = w >> 1, wn = w & 1;
  const int m0 = blockIdx.y * BM, n0 = blockIdx.x * BN;
  const int rl = l & 15, kg = l >> 4;

  f32x4 acc[4][4] = {};

  const int sr = t >> 2;
  const int gq = (t & 3) ^ (sr & 3);
  const unsigned short* aP0 = A  + (size_t)(m0 + sr) * K + gq * 8;
  const unsigned short* aP1 = A  + (size_t)(m0 + 64 + sr) * K + gq * 8;
  const unsigned short* bP0 = Bt + (size_t)(n0 + sr) * K + gq * 8;
  const unsigned short* bP1 = Bt + (size_t)(n0 + 64 + sr) * K + gq * 8;
  char* ldsA = (char*)As;
  char* ldsB = (char*)Bs;
  const int wb = w * 1024;

  const int nk = K / BK;
  for (int kt = 0; kt < nk; ++kt) {
    const int ko = kt * BK;
    __syncthreads();
    GLL16(aP0 + ko, ldsA + wb);
    GLL16(aP1 + ko, ldsA + 4096 + wb);
    GLL16(bP0 + ko, ldsB + wb);
    GLL16(bP1 + ko, ldsB + 4096 + wb);
    __syncthreads();
    short8 aF[4], bF[4];
    #pragma unroll
    for (int mi = 0; mi < 4; ++mi) {
      int r = wm * 64 + mi * 16 + rl;
      aF[mi] = *(const short8*)(ldsA + r * 64 + ((kg ^ (r & 3)) * 16));
    }
    #pragma unroll
    for (int ni = 0; ni < 4; ++ni) {
      int r = wn * 64 + ni * 16 + rl;
      bF[ni] = *(const short8*)(ldsB + r * 64 + ((kg ^ (r & 3)) * 16));
    }
    #pragma unroll
    for (int mi = 0; mi < 4; ++mi)
      #pragma unroll
      for (int ni = 0; ni < 4; ++ni)
        acc[mi][ni] = __builtin_amdgcn_mfma_f32_16x16x32_bf16(aF[mi], bF[ni], acc[mi][ni], 0, 0, 0);
  }

  // C/D layout (m89-verified): col = lane&15, row = (lane>>4)*4 + reg
  #pragma unroll
  for (int mi = 0; mi < 4; ++mi) {
    #pragma unroll
    for (int ni = 0; ni < 4; ++ni) {
      int row = m0 + wm * 64 + mi * 16 + kg * 4;
      int col = n0 + wn * 64 + ni * 16 + rl;
      #pragma unroll
      for (int r = 0; r < 4; ++r) {
        if constexpr (OUTF32)
          ((float*)C)[(size_t)(row + r) * N + col] = acc[mi][ni][r];
        else
          ((unsigned short*)C)[(size_t)(row + r) * N + col] = f2bf(acc[mi][ni][r]);
      }
    }
  }
}

// ---------------- RoPE (interleaved pairs) on Q and K regions of qkv --------

__global__ void k_rope(unsigned short* __restrict__ qkv,
                       const float* __restrict__ tc, const float* __restrict__ ts) {
  int id = blockIdx.x * 256 + threadIdx.x;     // MROWS * 1280
  int row = id / 1280, p = id % 1280;
  int col, d;
  if (p < 1024) { col = 2 * p;               d = p & 63; }
  else          { int pk = p - 1024; col = KOFF + 2 * pk; d = pk & 63; }
  int s = row & (SEQ - 1);
  float c = tc[s * 64 + d], sn = ts[s * 64 + d];
  unsigned int* pp = (unsigned int*)(qkv + (size_t)row * NQKV + col);
  unsigned int v = *pp;
  float x0 = bf2f((unsigned short)(v & 0xffffu));
  float x1 = bf2f((unsigned short)(v >> 16));
  float y0 = x0 * c - x1 * sn;
  float y1 = x1 * c + x0 * sn;
  *pp = (unsigned int)f2bf(y0) | ((unsigned int)f2bf(y1) << 16);
}

// ---------------- flash attention, causal, GQA ------------------------------
// 8 waves x 16 q-rows (QB=128), KVBLK=64; K/V via global_load_lds with
// pre-swizzled sources; 1D grid with complementary-pair decode for balance.

constexpr int QB = 128, KB = 64;

__global__ __launch_bounds__(512) void k_attn(const unsigned short* __restrict__ qkv,
                                              const unsigned short* __restrict__ vt,
                                              unsigned short* __restrict__ obuf) {
  __shared__ unsigned short Ks[KB * DH];        // [64][128], chunk-XOR ^(row&7)
  __shared__ unsigned short Vs[DH * KB];        // [128][64], chunk-XOR ^(row&7)
  __shared__ unsigned short Pw[8][16 * 72];     // per-wave P, padded stride 72

  const int t = threadIdx.x, l = t & 63, w = t >> 6;
  const int rl = l & 15, kg = l >> 4;

  // complementary-pair decode: ids i and i+256 get q-tiles qt and 15-qt
  const int id = blockIdx.x;                    // [0, 512)
  const int b = id >> 8;
  const int u = id & 255;
  const int h = u >> 4;
  const int qtr = u & 15;
  const int qt = b ? (15 - qtr) : qtr;
  const int q0 = qt * QB;
  const int kvh = h >> 2;

  const unsigned short* qbase = qkv + (size_t)b * SEQ * NQKV;
  const unsigned short* kbase = qbase + KOFF + kvh * DH;
  const unsigned short* vtb = vt + (size_t)(b * NKVH + kvh) * DH * SEQ;

  // staging sources: K chunks c=i*512+t (row=c>>4, q=c&15); V chunks (row=c>>3, q=c&7)
  const unsigned short* kp[2];
  const unsigned short* vp[2];
  #pragma unroll
  for (int i = 0; i < 2; ++i) {
    int c = i * 512 + t;
    int krow = c >> 4, kq = c & 15;
    kp[i] = kbase + (size_t)krow * NQKV + ((kq ^ (krow & 7)) << 3);
    int vrow = c >> 3, vq = c & 7;
    vp[i] = vtb + (size_t)vrow * SEQ + ((vq ^ (vrow & 7)) << 3);
  }

  const int qw0 = q0 + w * 16;

  // Q fragments hoisted: A[row=rl][k=kg*8+j], 4 k-steps
  short8 qF[4];
  {
    const size_t qr = (size_t)(qw0 + rl) * NQKV + h * DH;
    #pragma unroll
    for (int ks = 0; ks < 4; ++ks)
      qF[ks] = *(const short8*)(qbase + qr + ks * 32 + kg * 8);
  }

  f32x4 Oc[8] = {};
  float mr[4], lr[4];
  #pragma unroll
  for (int r = 0; r < 4; ++r) { mr[r] = -3e38f; lr[r] = 0.f; }

  unsigned short* pw = Pw[w];

  for (int kv0 = 0; kv0 < q0 + QB; kv0 += KB) {
    __syncthreads();
    #pragma unroll
    for (int i = 0; i < 2; ++i) {
      GLL16(kp[i] + (size_t)kv0 * NQKV, (char*)Ks + w * 1024 + i * 8192);
      GLL16(vp[i] + kv0,               (char*)Vs + w * 1024 + i * 8192);
    }
    __syncthreads();
    if (kv0 >= qw0 + 16) continue;   // fully masked for this wave (wave-uniform)

    // S = Q K^T : St[n], kv col tiles n of 16 (log2-domain scores)
    f32x4 St[4] = {};
    #pragma unroll
    for (int n = 0; n < 4; ++n) {
      const int krow = n * 16 + rl;
      #pragma unroll
      for (int ks = 0; ks < 4; ++ks) {
        short8 kF = *(const short8*)&Ks[krow * DH + (((ks * 4 + kg) ^ (rl & 7)) << 3)];
        St[n] = __builtin_amdgcn_mfma_f32_16x16x32_bf16(qF[ks], kF, St[n], 0, 0, 0);
      }
    }

    // online softmax in exp2 domain; lane's rows: kg*4+r
    float sfv[4];
    #pragma unroll
    for (int r = 0; r < 4; ++r) {
      const int qg = qw0 + kg * 4 + r;
      float e[4];
      float mx = -3e38f;
      #pragma unroll
      for (int n = 0; n < 4; ++n) {
        float s = St[n][r] * SM_L2;
        if (kv0 + n * 16 + rl > qg) s = -3e38f;
        e[n] = s;
        mx = fmaxf(mx, s);
      }
      #pragma unroll
      for (int dd = 1; dd < 16; dd <<= 1) mx = fmaxf(mx, __shfl_xor(mx, dd, 16));
      const float mnew = fmaxf(mr[r], mx);
      float rs = 0.f;
      #pragma unroll
      for (int n = 0; n < 4; ++n) { e[n] = exp2f(e[n] - mnew); rs += e[n]; }
      #pragma unroll
      for (int dd = 1; dd < 16; dd <<= 1) rs += __shfl_xor(rs, dd, 16);
      const float sf = exp2f(mr[r] - mnew);
      mr[r] = mnew;
      lr[r] = lr[r] * sf + rs;
      sfv[r] = sf;
      const int pr = kg * 4 + r;
      #pragma unroll
      for (int n = 0; n < 4; ++n) pw[pr * 72 + n * 16 + rl] = f2bf(e[n]);
    }

    // rescale O
    #pragma unroll
    for (int c = 0; c < 8; ++c)
      #pragma unroll
      for (int r = 0; r < 4; ++r) Oc[c][r] *= sfv[r];

    // PV: A = P[16][64] (row=rl, k=kv), B = V (col=d=rl, k=kv) from Vs rows
    short8 pF[2];
    #pragma unroll
    for (int ks2 = 0; ks2 < 2; ++ks2)
      pF[ks2] = *(const short8*)&pw[rl * 72 + ks2 * 32 + kg * 8];
    #pragma unroll
    for (int c = 0; c < 8; ++c) {
      const int vrow = c * 16 + rl;
      #pragma unroll
      for (int ks2 = 0; ks2 < 2; ++ks2) {
        short8 vF = *(const short8*)&Vs[vrow * KB + (((ks2 * 4 + kg) ^ (rl & 7)) << 3)];
        Oc[c] = __builtin_amdgcn_mfma_f32_16x16x32_bf16(pF[ks2], vF, Oc[c], 0, 0, 0);
      }
    }
  }

  // epilogue: O /= l, write bf16 [b*S+s][h*128+d]
  float inv[4];
  #pragma unroll
  for (int r = 0; r < 4; ++r) inv[r] = 1.0f / lr[r];
  #pragma unroll
  for (int c = 0; c < 8; ++c)
    #pragma unroll
    for (int r = 0; r < 4; ++r) {
      int row = b * SEQ + qw0 + kg * 4 + r;
      obuf[(size_t)row * DMODEL + h * DH + c * 16 + rl] = f2bf(Oc[c][r] * inv[r]);
    }
}

// ---------------- launch ----------------------------------------------------

extern "C" void kernel_launch(void* const* d_in, const int* in_sizes, int n_in,
                              void* d_out, int out_size, void* d_ws, size_t ws_size,
                              hipStream_t stream) {
  const float* x  = (const float*)d_in[0];
  const float* wq = (const float*)d_in[1];
  const float* wk = (const float*)d_in[2];
  const float* wv = (const float*)d_in[3];
  const float* wo = (const float*)d_in[4];
  float* out = (float*)d_out;

  unsigned short* xb  = (unsigned short*)d_ws;                 // 4096x2048
  unsigned short* wT  = xb  + (size_t)MROWS * DMODEL;          // 3072x2048 (q|k|v transposed)
  unsigned short* woT = wT  + (size_t)NQKV * DMODEL;           // 2048x2048
  unsigned short* qkv = woT + (size_t)DMODEL * DMODEL;         // 4096x3072
  unsigned short* ob  = qkv + (size_t)MROWS * NQKV;            // 4096x2048
  float* tc = (float*)(ob + (size_t)MROWS * DMODEL);           // 2048x64
  float* ts = tc + SEQ * 64;
  // vt reuses the wT region (wT dead after the QKV GEMM)
  unsigned short* vtG = wT;

  k_tables<<<dim3(SEQ * 64 / 256), dim3(256), 0, stream>>>(tc, ts);
  k_castx<<<dim3(MROWS * DMODEL / 4 / 256), dim3(256), 0, stream>>>(x, xb);
  k_wtrans<<<dim3(DMODEL / 32, 64), dim3(32, 8), 0, stream>>>(wq, wT, DMODEL);
  k_wtrans<<<dim3(NKVH * DH / 32, 64), dim3(32, 8), 0, stream>>>(wk, wT + (size_t)DMODEL * 2048, NKVH * DH);
  k_wtrans<<<dim3(NKVH * DH / 32, 64), dim3(32, 8), 0, stream>>>(wv, wT + (size_t)VOFF * 2048, NKVH * DH);
  k_wtrans<<<dim3(DMODEL / 32, 64), dim3(32, 8), 0, stream>>>(wo, woT, DMODEL);

  k_gemm_bt<false><<<dim3(NQKV / BN, MROWS / BM), dim3(256), 0, stream>>>(
      xb, wT, qkv, MROWS, NQKV, DMODEL);
  k_rope<<<dim3(MROWS * 1280 / 256), dim3(256), 0, stream>>>(qkv, tc, ts);
  k_vtrans<<<dim3(SEQ / 32, DH / 32, BATCH * NKVH), dim3(32, 8), 0, stream>>>(qkv, vtG);
  k_attn<<<dim3(512), dim3(512), 0, stream>>>(qkv, vtG, ob);
  k_gemm_bt<true><<<dim3(DMODEL / BN, MROWS / BM), dim3(256), 0, stream>>>(
      ob, woT, out, MROWS, DMODEL, DMODEL);
}